// Round 11
// baseline (486.300 us; speedup 1.0000x reference)
//
#include <hip/hip_runtime.h>
#include <hip/hip_bf16.h>
#include <cstdint>

typedef __attribute__((ext_vector_type(8))) short short8;
typedef __attribute__((ext_vector_type(4))) float f32x4;
typedef unsigned short u16;

__device__ __forceinline__ float b2f(u16 u) {
  union { unsigned int i; float f; } v; v.i = ((unsigned int)u) << 16; return v.f;
}
// hardware RNE f32->bf16
__device__ __forceinline__ u16 f2b(float f) {
  __hip_bfloat16 h = __float2bfloat16(f);
  union { __hip_bfloat16 h; u16 u; } v; v.h = h; return v.u;
}
__device__ __forceinline__ float silu_f(float x) { return x / (1.0f + __expf(-x)); }

__device__ __forceinline__ float loadF(const void* p, long i, int isf32) {
  if (isf32) return ((const float*)p)[i];
  return b2f(((const u16*)p)[i]);
}

// dtype sniff bit: f32 data viewed as u16 -> low halves are ~uniform-random;
// ~50% land outside bf16-exponent [2^-63, 2^65). Genuine bf16 N(0,1)/uniform
// data: none (zeros excluded).
__device__ __forceinline__ int sniffbit(u16 u) {
  unsigned e = (u >> 7) & 0xffu;
  return (e >= 0xC0u || (e < 0x40u && (u & 0x7fffu) != 0)) ? 1 : 0;
}

struct Ptrs { const void* p[20]; int n[20]; };

// f32 prepped-weight layout (float offsets)
#define FW_EW1 0
#define FW_UW1 384
#define FW_UW2 4480
#define FW_UB1 8576
#define FW_UB2 8640
#define FW_EB1 8704
#define FW_EB2 8768
#define FW_MB1 8832
#define FW_MB2 8896
#define FW_TOTAL 8960

// bf16 transposed image layout (u16 offsets)
#define IMG_EW2 0
#define IMG_MW1 4608
#define IMG_MW2 13312
#define IMG_TOTAL 17920

#define PREP_BLOCKS 105   // ceil((IMG_TOTAL + FW_TOTAL)/256)
#define HIST_BLOCKS 1024

// ---------------------------------------------------------------------------
// Kernel 1: histogram (XCD-sharded) | dtype detection.
// Blocks [0,HIST_BLOCKS) hist; [HIST_BLOCKS,+20) detect -> flags.
// ---------------------------------------------------------------------------
__global__ __launch_bounds__(256) void hist_detect_k(
    Ptrs a, const int* __restrict__ eidx, int* __restrict__ cnt8,
    int* __restrict__ flags, long E, int G)
{
  const int t = threadIdx.x;
  const int b = blockIdx.x;
  if (b < HIST_BLOCKS) {
    int* cs = cnt8 + (size_t)(b & 7) * G;
    long i = (long)b * 256 + t;
    const long stride = (long)HIST_BLOCKS * 256;
    for (; i < E; i += stride) {
      int tg = eidx[E + i];
      if (tg >= 0 && tg < G) atomicAdd(&cs[tg], 1);
    }
    return;
  }
  int j = b - HIST_BLOCKS;
  const u16* q = (const u16*)a.p[j];
  int n = a.n[j];
  int m = n < 4096 ? n : 4096;
  int cnt = 0;
  for (int i = t; i < m; i += 256) cnt += sniffbit(q[i]);
  __shared__ int tot;
  if (t == 0) tot = 0;
  __syncthreads();
  if (cnt) atomicAdd(&tot, cnt);
  __syncthreads();
  if (t == 0) flags[j] = (tot >= 2) ? 1 : 0;
}

// ---------------------------------------------------------------------------
// Kernel 2: scan (8G pairs, target-major) | weight prep | node MLP.
// Blocks [0,NB2) scan; [NB2,+PREP_BLOCKS) prep; rest node.
// ---------------------------------------------------------------------------
__global__ __launch_bounds__(256) void scan_prep_node_k(
    Ptrs a, const int* __restrict__ flags,
    const int* __restrict__ cnt8, int* __restrict__ cursor8,
    int* __restrict__ bsum,
    u16* __restrict__ img, float* __restrict__ fw,
    u16* __restrict__ hout, int nrows, int G, int NB2)
{
  const int t = threadIdx.x;
  const int b = blockIdx.x;

  if (b < NB2) {
    // ---- scan: 1024 (tg,c) pairs per block, j = tg*8+c ----
    __shared__ int sd[256];
    const long tot = 8L * G;
    long j0 = (long)b * 1024 + (long)t * 4;
    int v[4];
#pragma unroll
    for (int k = 0; k < 4; ++k) {
      long j = j0 + k;
      v[k] = (j < tot) ? cnt8[(size_t)(j & 7) * G + (j >> 3)] : 0;
    }
    int local = v[0] + v[1] + v[2] + v[3];
    sd[t] = local;
    __syncthreads();
    for (int off = 1; off < 256; off <<= 1) {
      int x2 = (t >= off) ? sd[t - off] : 0;
      __syncthreads();
      sd[t] += x2;
      __syncthreads();
    }
    int p = sd[t] - local;
#pragma unroll
    for (int k = 0; k < 4; ++k) {
      long j = j0 + k;
      if (j < tot) cursor8[(size_t)(j & 7) * G + (j >> 3)] = p;
      p += v[k];
    }
    if (t == 255) bsum[b] = sd[255];
    return;
  }

  if (b < NB2 + PREP_BLOCKS) {
    // ---- weight prep ----
    int i = (b - NB2) * 256 + t;
    if (i < IMG_TOTAL) {
      const void* bp; int fl; long si; bool real;
      if (i < IMG_MW1) { int nn = i / 72, k = i % 72; bp = a.p[10]; fl = flags[10]; real = k < 64; si = (long)k * 64 + nn; }
      else if (i < IMG_MW2) { int t2 = i - IMG_MW1; int nn = t2 / 136, k = t2 % 136; bp = a.p[12]; fl = flags[12]; real = k < 128; si = (long)k * 64 + nn; }
      else { int t2 = i - IMG_MW2; int nn = t2 / 72, k = t2 % 72; bp = a.p[14]; fl = flags[14]; real = k < 64; si = (long)k * 64 + nn; }
      u16 val = 0;
      if (real) val = f2b(loadF(bp, si, fl));
      img[i] = val;
    } else if (i < IMG_TOTAL + FW_TOTAL) {
      int j = i - IMG_TOTAL;
      const void* bp; int fl; long si;
      if (j < 384)        { bp = a.p[8];  fl = flags[8];  si = j; }
      else if (j < 4480)  { bp = a.p[16]; fl = flags[16]; si = j - 384; }
      else if (j < 8576)  { bp = a.p[18]; fl = flags[18]; si = j - 4480; }
      else {
        int bb = j - 8576; int seg = bb >> 6; si = bb & 63;
        switch (seg) {
          case 0: bp = a.p[17]; fl = flags[17]; break;
          case 1: bp = a.p[19]; fl = flags[19]; break;
          case 2: bp = a.p[9];  fl = flags[9];  break;
          case 3: bp = a.p[11]; fl = flags[11]; break;
          case 4: bp = a.p[13]; fl = flags[13]; break;
          default: bp = a.p[15]; fl = flags[15]; break;
        }
      }
      fw[j] = loadF(bp, si, fl);
    }
    return;
  }

  // ---- node MLP ----
  __shared__ float xs[64][68];
  __shared__ float w1s[64][68];
  __shared__ float w2s[64][68];
  __shared__ float b1s[64];
  __shared__ float b2s[64];
  const void* x = a.p[0];
  const int xf = flags[0], f1 = flags[4], fb1 = flags[5], f2 = flags[6], fb2 = flags[7];
  const long rbase = (long)(b - NB2 - PREP_BLOCKS) * 64;
  for (int i = t; i < 4096; i += 256) {
    int k = i >> 6, cc = i & 63;
    w1s[k][cc] = loadF(a.p[4], i, f1);
    w2s[k][cc] = loadF(a.p[6], i, f2);
  }
  if (t < 64) { b1s[t] = loadF(a.p[5], t, fb1); b2s[t] = loadF(a.p[7], t, fb2); }
  {
    int row = t >> 2, ch = t & 3;
    long rg = rbase + row;
    if (rg < nrows) {
      if (xf) {
        const float* xp = (const float*)x + rg * 64 + ch * 16;
#pragma unroll
        for (int m = 0; m < 16; ++m) xs[row][ch * 16 + m] = xp[m];
      } else {
        const u16* xp = (const u16*)x + rg * 64 + ch * 16;
#pragma unroll
        for (int m = 0; m < 16; ++m) xs[row][ch * 16 + m] = b2f(xp[m]);
      }
    } else {
#pragma unroll
      for (int m = 0; m < 16; ++m) xs[row][ch * 16 + m] = 0.f;
    }
  }
  __syncthreads();
  const int r0 = (t >> 4) * 4, c0 = (t & 15) * 4;
  float acc[4][4];
#pragma unroll
  for (int i = 0; i < 4; ++i)
#pragma unroll
    for (int j = 0; j < 4; ++j) acc[i][j] = b1s[c0 + j];
  for (int k = 0; k < 64; ++k) {
    float w0 = w1s[k][c0], w1v = w1s[k][c0 + 1], w2v = w1s[k][c0 + 2], w3v = w1s[k][c0 + 3];
#pragma unroll
    for (int i = 0; i < 4; ++i) {
      float av = xs[r0 + i][k];
      acc[i][0] = fmaf(av, w0, acc[i][0]);
      acc[i][1] = fmaf(av, w1v, acc[i][1]);
      acc[i][2] = fmaf(av, w2v, acc[i][2]);
      acc[i][3] = fmaf(av, w3v, acc[i][3]);
    }
  }
  __syncthreads();
#pragma unroll
  for (int i = 0; i < 4; ++i)
#pragma unroll
    for (int j = 0; j < 4; ++j) xs[r0 + i][c0 + j] = silu_f(acc[i][j]);
  __syncthreads();
  float acc2[4][4];
#pragma unroll
  for (int i = 0; i < 4; ++i)
#pragma unroll
    for (int j = 0; j < 4; ++j) acc2[i][j] = b2s[c0 + j];
  for (int k = 0; k < 64; ++k) {
    float w0 = w2s[k][c0], w1v = w2s[k][c0 + 1], w2v = w2s[k][c0 + 2], w3v = w2s[k][c0 + 3];
#pragma unroll
    for (int i = 0; i < 4; ++i) {
      float av = xs[r0 + i][k];
      acc2[i][0] = fmaf(av, w0, acc2[i][0]);
      acc2[i][1] = fmaf(av, w1v, acc2[i][1]);
      acc2[i][2] = fmaf(av, w2v, acc2[i][2]);
      acc2[i][3] = fmaf(av, w3v, acc2[i][3]);
    }
  }
#pragma unroll
  for (int i = 0; i < 4; ++i) {
    long rg = rbase + r0 + i;
    if (rg < nrows) {
#pragma unroll
      for (int j = 0; j < 4; ++j) hout[rg * 64 + c0 + j] = f2b(acc2[i][j]);
    }
  }
}

// ---------------------------------------------------------------------------
// Kernel 3: scatter into sorted order, XCD-sharded cursors (c = blockIdx&7);
// inline top-level scan of bsum (<=256 chunks). NT stores for pkS.
// pack: src (17 bits) | tgt<<17 (15 bits)
// ---------------------------------------------------------------------------
__global__ __launch_bounds__(256) void scat_k(const int* __restrict__ eidx,
                                              int* __restrict__ cursor8,
                                              const int* __restrict__ bsum,
                                              unsigned int* __restrict__ pkS,
                                              int* __restrict__ evp,
                                              long E, int G, int NB2) {
  __shared__ int bo[256];
  const int t = threadIdx.x;
  int v = (t < NB2) ? bsum[t] : 0;
  bo[t] = v;
  __syncthreads();
  for (int off = 1; off < 256; off <<= 1) {
    int x2 = (t >= off) ? bo[t - off] : 0;
    __syncthreads();
    bo[t] += x2;
    __syncthreads();
  }
  if (blockIdx.x == 0 && t == 0) *evp = bo[NB2 - 1];
  int excl = bo[t] - v;
  __syncthreads();
  bo[t] = excl;
  __syncthreads();
  const int c = blockIdx.x & 7;
  int* cur = cursor8 + (size_t)c * G;
  long i = (long)blockIdx.x * 256 + t;
  const long stride = (long)gridDim.x * 256;
  for (; i < E; i += stride) {
    int tg = eidx[E + i];
    if (tg >= 0 && tg < G) {
      int s = eidx[i];
      long j = ((long)tg << 3) | c;
      int p = atomicAdd(&cur[tg], 1) + bo[j >> 10];
      __builtin_nontemporal_store((unsigned int)s | ((unsigned int)tg << 17), pkS + p);
    }
  }
}

// ---------------------------------------------------------------------------
// Kernel 4: edge pipeline, wave-private stages, 23 KB LDS -> 7 blocks/CU.
// Per-wave LDS pool: ef1[16][72] | hA(e_feat2)[16][72]; msgf f32[16][66]
// overlays the wave's own pool after S4's A-frag reads (same-wave DS ops are
// in-order; wave_barrier pins compiler ordering). h_node A-fragments loaded
// directly from global in S3 (no LDS staging). Geometry gather distributed
// across waves (lanes 0..15 each).
// ---------------------------------------------------------------------------
#define ETILES 4

__global__ __launch_bounds__(256, 7) void edge_kernel(
    const void* node_pos, const void* grid_pos, const void* orient,
    const unsigned int* __restrict__ pkS, const int* __restrict__ evp,
    const u16* __restrict__ h_node, const u16* __restrict__ img,
    const float* __restrict__ fw, const int* __restrict__ flags,
    float* __restrict__ sums, int G)
{
  __shared__ __align__(16) u16 pool[4][2304];  // per wave 4608 B
  __shared__ float eaf[64][6];
  __shared__ float w1e[6][64];
  __shared__ float biasE[4][64];
  __shared__ int tgt_s[64];
  __shared__ int src_s[64];

  const int t = threadIdx.x;
  const int pf = flags[1], gf = flags[2], of = flags[3];
  const int Ev = *evp;
  for (int i = t; i < 384; i += 256) w1e[i / 64][i % 64] = fw[FW_EW1 + i];
  { int seg = t >> 6, cc = t & 63; biasE[seg][cc] = fw[FW_EB1 + seg * 64 + cc]; }
  __syncthreads();

  const int lane = t & 63, w = t >> 6;
  const int q = lane >> 4, c = lane & 15;
  const int m0 = w * 16;
  u16 (* __restrict__ ef1w)[72] = (u16 (*)[72])&pool[w][0];
  u16 (* __restrict__ hAw)[72]  = (u16 (*)[72])&pool[w][1152];
  float (* __restrict__ msgfw)[66] = (float (*)[66])&pool[w][0];  // 4224 <= 4608
  const u16* wE2 = img + IMG_EW2;
  const u16* wM1 = img + IMG_MW1;
  const u16* wM2 = img + IMG_MW2;
  const f32x4 z = {0.f, 0.f, 0.f, 0.f};

  for (int tile = 0; tile < ETILES; ++tile) {
    long base = ((long)blockIdx.x * ETILES + tile) * 64;
    if (base >= Ev) break;
    __syncthreads();  // prev tile's msgf/tgt_s fully consumed
    // gather: each wave's lanes 0..15 handle its own 16 edges
    if (lane < 16) {
      long eg = base + m0 + lane;
      int s = 0, tg = -1;
      if (eg < Ev) {
        unsigned int pk = pkS[eg];
        s = (int)(pk & 0x1FFFFu);
        tg = (int)(pk >> 17);
      }
      tgt_s[m0 + lane] = tg;
      src_s[m0 + lane] = s;
      int tgc = (tg >= 0) ? tg : 0;
      float ps[3], rel[3], tr[3];
#pragma unroll
      for (int i = 0; i < 3; ++i) {
        ps[i] = loadF(node_pos, (long)s * 3 + i, pf);
        rel[i] = loadF(grid_pos, (long)tgc * 3 + i, gf) - ps[i];
      }
#pragma unroll
      for (int j = 0; j < 3; ++j) tr[j] = 0.f;
#pragma unroll
      for (int i = 0; i < 3; ++i)
#pragma unroll
        for (int j = 0; j < 3; ++j)
          tr[j] = fmaf(rel[i], loadF(orient, (long)s * 9 + i * 3 + j, of), tr[j]);
      eaf[m0 + lane][0] = ps[0]; eaf[m0 + lane][1] = ps[1]; eaf[m0 + lane][2] = ps[2];
      eaf[m0 + lane][3] = tr[0]; eaf[m0 + lane][4] = tr[1]; eaf[m0 + lane][5] = tr[2];
    }
    __syncthreads();  // gather committed

    // S1: edge MLP layer1 (K=6) f32 VALU -> silu -> ef1w (bf16)
    {
      int e = lane >> 2;              // wave-local row
      int eb = m0 + e;                // block row (eaf)
      int c0 = (lane & 3) * 16;
      float a0 = eaf[eb][0], a1 = eaf[eb][1], a2 = eaf[eb][2];
      float a3 = eaf[eb][3], a4 = eaf[eb][4], a5 = eaf[eb][5];
      __align__(16) u16 tmp[16];
#pragma unroll
      for (int j = 0; j < 16; ++j) {
        int cc = c0 + j;
        float acc = biasE[0][cc];
        acc = fmaf(a0, w1e[0][cc], acc);
        acc = fmaf(a1, w1e[1][cc], acc);
        acc = fmaf(a2, w1e[2][cc], acc);
        acc = fmaf(a3, w1e[3][cc], acc);
        acc = fmaf(a4, w1e[4][cc], acc);
        acc = fmaf(a5, w1e[5][cc], acc);
        tmp[j] = f2b(silu_f(acc));
      }
      *(short8*)&ef1w[e][c0] = *(const short8*)tmp;
      *(short8*)&ef1w[e][c0 + 8] = *(const short8*)(tmp + 8);
    }
    __syncthreads();
    // S2: edge MLP layer2 (K=64) -> hAw (e_feat2, bf16)
    {
      short8 a0 = *(const short8*)&ef1w[c][q * 8];
      short8 a1 = *(const short8*)&ef1w[c][32 + q * 8];
#pragma unroll
      for (int nt = 0; nt < 4; ++nt) {
        short8 b0 = *(const short8*)&wE2[(nt * 16 + c) * 72 + q * 8];
        short8 b1v = *(const short8*)&wE2[(nt * 16 + c) * 72 + 32 + q * 8];
        f32x4 acc = __builtin_amdgcn_mfma_f32_16x16x32_bf16(a0, b0, z, 0, 0, 0);
        acc = __builtin_amdgcn_mfma_f32_16x16x32_bf16(a1, b1v, acc, 0, 0, 0);
#pragma unroll
        for (int r = 0; r < 4; ++r) {
          int row = q * 4 + r, col = nt * 16 + c;
          hAw[row][col] = f2b(acc[r] + biasE[1][col]);
        }
      }
    }
    __syncthreads();
    // S3: msg MLP layer1 (K=128) -> silu -> ef1w.
    // a0/a1 (h_node half) loaded DIRECTLY from global; a2/a3 from hAw.
    {
      const u16* hp = h_node + (long)src_s[m0 + c] * 64;
      short8 a0 = *(const short8*)(hp + q * 8);
      short8 a1 = *(const short8*)(hp + 32 + q * 8);
      short8 a2 = *(const short8*)&hAw[c][q * 8];
      short8 a3 = *(const short8*)&hAw[c][32 + q * 8];
#pragma unroll
      for (int nt = 0; nt < 4; ++nt) {
        const u16* wp = &wM1[(nt * 16 + c) * 136];
        f32x4 acc = __builtin_amdgcn_mfma_f32_16x16x32_bf16(a0, *(const short8*)(wp + q * 8), z, 0, 0, 0);
        acc = __builtin_amdgcn_mfma_f32_16x16x32_bf16(a1, *(const short8*)(wp + 32 + q * 8), acc, 0, 0, 0);
        acc = __builtin_amdgcn_mfma_f32_16x16x32_bf16(a2, *(const short8*)(wp + 64 + q * 8), acc, 0, 0, 0);
        acc = __builtin_amdgcn_mfma_f32_16x16x32_bf16(a3, *(const short8*)(wp + 96 + q * 8), acc, 0, 0, 0);
#pragma unroll
        for (int r = 0; r < 4; ++r) {
          int row = q * 4 + r, col = nt * 16 + c;
          ef1w[row][col] = f2b(silu_f(acc[r] + biasE[2][col]));
        }
      }
    }
    __syncthreads();
    // S4: msg MLP layer2 (K=64) -> msgfw (f32, +bias), overlaying the pool.
    // Reads (a0,a1) precede writes in the wave's instruction stream.
    {
      short8 a0 = *(const short8*)&ef1w[c][q * 8];
      short8 a1 = *(const short8*)&ef1w[c][32 + q * 8];
      __builtin_amdgcn_wave_barrier();   // pin read-before-overlay-write
#pragma unroll
      for (int nt = 0; nt < 4; ++nt) {
        short8 b0 = *(const short8*)&wM2[(nt * 16 + c) * 72 + q * 8];
        short8 b1v = *(const short8*)&wM2[(nt * 16 + c) * 72 + 32 + q * 8];
        f32x4 acc = __builtin_amdgcn_mfma_f32_16x16x32_bf16(a0, b0, z, 0, 0, 0);
        acc = __builtin_amdgcn_mfma_f32_16x16x32_bf16(a1, b1v, acc, 0, 0, 0);
#pragma unroll
        for (int r = 0; r < 4; ++r) {
          int row = q * 4 + r, col = nt * 16 + c;
          msgfw[row][col] = acc[r] + biasE[3][col];
        }
      }
    }
    __builtin_amdgcn_wave_barrier();
    // Run-reduction over the wave's 16 rows; col = lane. tgt_s boundary
    // peeks are cross-wave but written at gather (stable since last sync).
    {
      int col = lane;
      int cur = tgt_s[m0];
      float run = msgfw[0][col];
      bool lopen = (m0 == 0) ? true : (tgt_s[m0 - 1] == cur);
#pragma unroll
      for (int r2 = 1; r2 < 16; ++r2) {
        int tg = tgt_s[m0 + r2];
        float v = msgfw[r2][col];
        if (tg == cur) {
          run += v;
        } else {
          if (cur >= 0) {
            if (lopen) unsafeAtomicAdd(&sums[(long)cur * 64 + col], run);
            else sums[(long)cur * 64 + col] = run;
          }
          cur = tg; run = v; lopen = false;
        }
      }
      bool ropen = (m0 + 16 >= 64) ? true : (tgt_s[m0 + 16] == cur);
      if (cur >= 0) {
        if (lopen || ropen) unsafeAtomicAdd(&sums[(long)cur * 64 + col], run);
        else sums[(long)cur * 64 + col] = run;
      }
    }
  }
}

// ---------------------------------------------------------------------------
// Kernel 5: scatter-mean (sum of 8 count shards) + update MLP -> f32 out
// ---------------------------------------------------------------------------
__global__ __launch_bounds__(256) void upd_mlp(
    const float* __restrict__ sums, const int* __restrict__ cnt8,
    const float* __restrict__ fw, float* __restrict__ out, int nrows)
{
  __shared__ float xs[64][68];
  __shared__ float w1s[64][68];
  __shared__ float w2s[64][68];
  __shared__ float b1s[64];
  __shared__ float b2s[64];
  const int t = threadIdx.x;
  const long rbase = (long)blockIdx.x * 64;
  for (int i = t; i < 4096; i += 256) {
    int k = i >> 6, cc = i & 63;
    w1s[k][cc] = fw[FW_UW1 + i];
    w2s[k][cc] = fw[FW_UW2 + i];
  }
  if (t < 64) { b1s[t] = fw[FW_UB1 + t]; b2s[t] = fw[FW_UB2 + t]; }
  {
    int row = t >> 2, ch = t & 3;
    long rg = rbase + row;
    if (rg < nrows) {
      int cn = 0;
#pragma unroll
      for (int cc = 0; cc < 8; ++cc) cn += cnt8[(size_t)cc * nrows + rg];
      float inv = 1.0f / fmaxf((float)cn, 1.0f);
      const float* p = sums + rg * 64 + ch * 16;
#pragma unroll
      for (int m = 0; m < 16; ++m) xs[row][ch * 16 + m] = p[m] * inv;
    } else {
#pragma unroll
      for (int m = 0; m < 16; ++m) xs[row][ch * 16 + m] = 0.f;
    }
  }
  __syncthreads();
  const int r0 = (t >> 4) * 4, c0 = (t & 15) * 4;
  float acc[4][4];
#pragma unroll
  for (int i = 0; i < 4; ++i)
#pragma unroll
    for (int j = 0; j < 4; ++j) acc[i][j] = b1s[c0 + j];
  for (int k = 0; k < 64; ++k) {
    float w0 = w1s[k][c0], w1v = w1s[k][c0 + 1], w2v = w1s[k][c0 + 2], w3v = w1s[k][c0 + 3];
#pragma unroll
    for (int i = 0; i < 4; ++i) {
      float av = xs[r0 + i][k];
      acc[i][0] = fmaf(av, w0, acc[i][0]);
      acc[i][1] = fmaf(av, w1v, acc[i][1]);
      acc[i][2] = fmaf(av, w2v, acc[i][2]);
      acc[i][3] = fmaf(av, w3v, acc[i][3]);
    }
  }
  __syncthreads();
#pragma unroll
  for (int i = 0; i < 4; ++i)
#pragma unroll
    for (int j = 0; j < 4; ++j) xs[r0 + i][c0 + j] = silu_f(acc[i][j]);
  __syncthreads();
  float acc2[4][4];
#pragma unroll
  for (int i = 0; i < 4; ++i)
#pragma unroll
    for (int j = 0; j < 4; ++j) acc2[i][j] = b2s[c0 + j];
  for (int k = 0; k < 64; ++k) {
    float w0 = w2s[k][c0], w1v = w2s[k][c0 + 1], w2v = w2s[k][c0 + 2], w3v = w2s[k][c0 + 3];
#pragma unroll
    for (int i = 0; i < 4; ++i) {
      float av = xs[r0 + i][k];
      acc2[i][0] = fmaf(av, w0, acc2[i][0]);
      acc2[i][1] = fmaf(av, w1v, acc2[i][1]);
      acc2[i][2] = fmaf(av, w2v, acc2[i][2]);
      acc2[i][3] = fmaf(av, w3v, acc2[i][3]);
    }
  }
#pragma unroll
  for (int i = 0; i < 4; ++i) {
    long rg = rbase + r0 + i;
    if (rg < nrows) {
#pragma unroll
      for (int j = 0; j < 4; ++j) out[rg * 64 + c0 + j] = acc2[i][j];
    }
  }
}

// ---------------------------------------------------------------------------
extern "C" void kernel_launch(void* const* d_in, const int* in_sizes, int n_in,
                              void* d_out, int out_size, void* d_ws, size_t ws_size,
                              hipStream_t stream) {
  const int N = in_sizes[1] / 3;
  const int G = in_sizes[2] / 3;
  const long E = (long)in_sizes[4] / 2;
  const int NB2 = (int)((8L * G + 1023) / 1024);   // <=256 for G<=32768
  const int nodeBlocks = (N + 63) / 64;

  char* ws = (char*)d_ws;
  float* sums = (float*)ws;
  size_t off = (size_t)G * 256;
  int* cnt8 = (int*)(ws + off);     off += (size_t)G * 32;   // 8 shards
  int* cursor8 = (int*)(ws + off);  off += (size_t)G * 32;
  int* bsum = (int*)(ws + off);     off += 1024;
  int* evp = (int*)(ws + off);      off += 256;
  int* flags = (int*)(ws + off);    off += 256;
  unsigned int* pkS = (unsigned int*)(ws + off); off += (size_t)E * 4;
  u16* h_node = (u16*)(ws + off);   off += (size_t)N * 128;
  u16* img = (u16*)(ws + off);      off += (size_t)IMG_TOTAL * 2;
  float* fw = (float*)(ws + off);

  // zero sums + cnt8 (ws poisoned 0xAA before every timed launch)
  hipMemsetAsync(ws, 0, (size_t)G * 288, stream);

  Ptrs a;
  const int map[20] = {0,1,2,3, 5,6,7,8, 9,10,11,12, 13,14,15,16, 17,18,19,20};
  for (int i = 0; i < 20; ++i) { a.p[i] = d_in[map[i]]; a.n[i] = in_sizes[map[i]]; }

  hist_detect_k<<<HIST_BLOCKS + 20, 256, 0, stream>>>(
      a, (const int*)d_in[4], cnt8, flags, E, G);
  scan_prep_node_k<<<NB2 + PREP_BLOCKS + nodeBlocks, 256, 0, stream>>>(
      a, flags, cnt8, cursor8, bsum, img, fw, h_node, N, G, NB2);
  scat_k<<<1024, 256, 0, stream>>>((const int*)d_in[4], cursor8, bsum, pkS, evp, E, G, NB2);
  edge_kernel<<<(int)((E + ETILES * 64 - 1) / (ETILES * 64)), 256, 0, stream>>>(
      d_in[1], d_in[2], d_in[3], pkS, evp, h_node, img, fw, flags, sums, G);
  upd_mlp<<<(G + 63) / 64, 256, 0, stream>>>(sums, cnt8, fw, (float*)d_out, G);
}

// Round 12
// 462.441 us; speedup vs baseline: 1.0516x; 1.0516x over previous
//
#include <hip/hip_runtime.h>
#include <hip/hip_bf16.h>
#include <cstdint>

typedef __attribute__((ext_vector_type(8))) short short8;
typedef __attribute__((ext_vector_type(4))) float f32x4;
typedef unsigned short u16;

__device__ __forceinline__ float b2f(u16 u) {
  union { unsigned int i; float f; } v; v.i = ((unsigned int)u) << 16; return v.f;
}
// hardware RNE f32->bf16
__device__ __forceinline__ u16 f2b(float f) {
  __hip_bfloat16 h = __float2bfloat16(f);
  union { __hip_bfloat16 h; u16 u; } v; v.h = h; return v.u;
}
__device__ __forceinline__ float silu_f(float x) { return x / (1.0f + __expf(-x)); }

__device__ __forceinline__ float loadF(const void* p, long i, int isf32) {
  if (isf32) return ((const float*)p)[i];
  return b2f(((const u16*)p)[i]);
}

// dtype sniff bit: f32 data viewed as u16 -> low halves are ~uniform-random;
// ~50% land outside bf16-exponent [2^-63, 2^65). Genuine bf16 N(0,1)/uniform
// data: none (zeros excluded).
__device__ __forceinline__ int sniffbit(u16 u) {
  unsigned e = (u >> 7) & 0xffu;
  return (e >= 0xC0u || (e < 0x40u && (u & 0x7fffu) != 0)) ? 1 : 0;
}

struct Ptrs { const void* p[20]; int n[20]; };

// f32 prepped-weight layout (float offsets)
#define FW_EW1 0
#define FW_UW1 384
#define FW_UW2 4480
#define FW_UB1 8576
#define FW_UB2 8640
#define FW_EB1 8704
#define FW_EB2 8768
#define FW_MB1 8832
#define FW_MB2 8896
#define FW_TOTAL 8960

// bf16 transposed image layout (u16 offsets)
#define IMG_EW2 0
#define IMG_MW1 4608
#define IMG_MW2 13312
#define IMG_TOTAL 17920

#define PREP_BLOCKS 105   // ceil((IMG_TOTAL + FW_TOTAL)/256)
#define HIST_BLOCKS 1024

// ---------------------------------------------------------------------------
// Kernel 1: histogram (XCD-sharded) | dtype detection.
// ---------------------------------------------------------------------------
__global__ __launch_bounds__(256) void hist_detect_k(
    Ptrs a, const int* __restrict__ eidx, int* __restrict__ cnt8,
    int* __restrict__ flags, long E, int G)
{
  const int t = threadIdx.x;
  const int b = blockIdx.x;
  if (b < HIST_BLOCKS) {
    int* cs = cnt8 + (size_t)(b & 7) * G;
    long i = (long)b * 256 + t;
    const long stride = (long)HIST_BLOCKS * 256;
    for (; i < E; i += stride) {
      int tg = eidx[E + i];
      if (tg >= 0 && tg < G) atomicAdd(&cs[tg], 1);
    }
    return;
  }
  int j = b - HIST_BLOCKS;
  const u16* q = (const u16*)a.p[j];
  int n = a.n[j];
  int m = n < 4096 ? n : 4096;
  int cnt = 0;
  for (int i = t; i < m; i += 256) cnt += sniffbit(q[i]);
  __shared__ int tot;
  if (t == 0) tot = 0;
  __syncthreads();
  if (cnt) atomicAdd(&tot, cnt);
  __syncthreads();
  if (t == 0) flags[j] = (tot >= 2) ? 1 : 0;
}

// ---------------------------------------------------------------------------
// Kernel 2: scan (8G pairs, target-major) | weight prep | node MLP.
// ---------------------------------------------------------------------------
__global__ __launch_bounds__(256) void scan_prep_node_k(
    Ptrs a, const int* __restrict__ flags,
    const int* __restrict__ cnt8, int* __restrict__ cursor8,
    int* __restrict__ bsum,
    u16* __restrict__ img, float* __restrict__ fw,
    u16* __restrict__ hout, int nrows, int G, int NB2)
{
  const int t = threadIdx.x;
  const int b = blockIdx.x;

  if (b < NB2) {
    __shared__ int sd[256];
    const long tot = 8L * G;
    long j0 = (long)b * 1024 + (long)t * 4;
    int v[4];
#pragma unroll
    for (int k = 0; k < 4; ++k) {
      long j = j0 + k;
      v[k] = (j < tot) ? cnt8[(size_t)(j & 7) * G + (j >> 3)] : 0;
    }
    int local = v[0] + v[1] + v[2] + v[3];
    sd[t] = local;
    __syncthreads();
    for (int off = 1; off < 256; off <<= 1) {
      int x2 = (t >= off) ? sd[t - off] : 0;
      __syncthreads();
      sd[t] += x2;
      __syncthreads();
    }
    int p = sd[t] - local;
#pragma unroll
    for (int k = 0; k < 4; ++k) {
      long j = j0 + k;
      if (j < tot) cursor8[(size_t)(j & 7) * G + (j >> 3)] = p;
      p += v[k];
    }
    if (t == 255) bsum[b] = sd[255];
    return;
  }

  if (b < NB2 + PREP_BLOCKS) {
    int i = (b - NB2) * 256 + t;
    if (i < IMG_TOTAL) {
      const void* bp; int fl; long si; bool real;
      if (i < IMG_MW1) { int nn = i / 72, k = i % 72; bp = a.p[10]; fl = flags[10]; real = k < 64; si = (long)k * 64 + nn; }
      else if (i < IMG_MW2) { int t2 = i - IMG_MW1; int nn = t2 / 136, k = t2 % 136; bp = a.p[12]; fl = flags[12]; real = k < 128; si = (long)k * 64 + nn; }
      else { int t2 = i - IMG_MW2; int nn = t2 / 72, k = t2 % 72; bp = a.p[14]; fl = flags[14]; real = k < 64; si = (long)k * 64 + nn; }
      u16 val = 0;
      if (real) val = f2b(loadF(bp, si, fl));
      img[i] = val;
    } else if (i < IMG_TOTAL + FW_TOTAL) {
      int j = i - IMG_TOTAL;
      const void* bp; int fl; long si;
      if (j < 384)        { bp = a.p[8];  fl = flags[8];  si = j; }
      else if (j < 4480)  { bp = a.p[16]; fl = flags[16]; si = j - 384; }
      else if (j < 8576)  { bp = a.p[18]; fl = flags[18]; si = j - 4480; }
      else {
        int bb = j - 8576; int seg = bb >> 6; si = bb & 63;
        switch (seg) {
          case 0: bp = a.p[17]; fl = flags[17]; break;
          case 1: bp = a.p[19]; fl = flags[19]; break;
          case 2: bp = a.p[9];  fl = flags[9];  break;
          case 3: bp = a.p[11]; fl = flags[11]; break;
          case 4: bp = a.p[13]; fl = flags[13]; break;
          default: bp = a.p[15]; fl = flags[15]; break;
        }
      }
      fw[j] = loadF(bp, si, fl);
    }
    return;
  }

  // ---- node MLP ----
  __shared__ float xs[64][68];
  __shared__ float w1s[64][68];
  __shared__ float w2s[64][68];
  __shared__ float b1s[64];
  __shared__ float b2s[64];
  const void* x = a.p[0];
  const int xf = flags[0], f1 = flags[4], fb1 = flags[5], f2 = flags[6], fb2 = flags[7];
  const long rbase = (long)(b - NB2 - PREP_BLOCKS) * 64;
  for (int i = t; i < 4096; i += 256) {
    int k = i >> 6, cc = i & 63;
    w1s[k][cc] = loadF(a.p[4], i, f1);
    w2s[k][cc] = loadF(a.p[6], i, f2);
  }
  if (t < 64) { b1s[t] = loadF(a.p[5], t, fb1); b2s[t] = loadF(a.p[7], t, fb2); }
  {
    int row = t >> 2, ch = t & 3;
    long rg = rbase + row;
    if (rg < nrows) {
      if (xf) {
        const float* xp = (const float*)x + rg * 64 + ch * 16;
#pragma unroll
        for (int m = 0; m < 16; ++m) xs[row][ch * 16 + m] = xp[m];
      } else {
        const u16* xp = (const u16*)x + rg * 64 + ch * 16;
#pragma unroll
        for (int m = 0; m < 16; ++m) xs[row][ch * 16 + m] = b2f(xp[m]);
      }
    } else {
#pragma unroll
      for (int m = 0; m < 16; ++m) xs[row][ch * 16 + m] = 0.f;
    }
  }
  __syncthreads();
  const int r0 = (t >> 4) * 4, c0 = (t & 15) * 4;
  float acc[4][4];
#pragma unroll
  for (int i = 0; i < 4; ++i)
#pragma unroll
    for (int j = 0; j < 4; ++j) acc[i][j] = b1s[c0 + j];
  for (int k = 0; k < 64; ++k) {
    float w0 = w1s[k][c0], w1v = w1s[k][c0 + 1], w2v = w1s[k][c0 + 2], w3v = w1s[k][c0 + 3];
#pragma unroll
    for (int i = 0; i < 4; ++i) {
      float av = xs[r0 + i][k];
      acc[i][0] = fmaf(av, w0, acc[i][0]);
      acc[i][1] = fmaf(av, w1v, acc[i][1]);
      acc[i][2] = fmaf(av, w2v, acc[i][2]);
      acc[i][3] = fmaf(av, w3v, acc[i][3]);
    }
  }
  __syncthreads();
#pragma unroll
  for (int i = 0; i < 4; ++i)
#pragma unroll
    for (int j = 0; j < 4; ++j) xs[r0 + i][c0 + j] = silu_f(acc[i][j]);
  __syncthreads();
  float acc2[4][4];
#pragma unroll
  for (int i = 0; i < 4; ++i)
#pragma unroll
    for (int j = 0; j < 4; ++j) acc2[i][j] = b2s[c0 + j];
  for (int k = 0; k < 64; ++k) {
    float w0 = w2s[k][c0], w1v = w2s[k][c0 + 1], w2v = w2s[k][c0 + 2], w3v = w2s[k][c0 + 3];
#pragma unroll
    for (int i = 0; i < 4; ++i) {
      float av = xs[r0 + i][k];
      acc2[i][0] = fmaf(av, w0, acc2[i][0]);
      acc2[i][1] = fmaf(av, w1v, acc2[i][1]);
      acc2[i][2] = fmaf(av, w2v, acc2[i][2]);
      acc2[i][3] = fmaf(av, w3v, acc2[i][3]);
    }
  }
#pragma unroll
  for (int i = 0; i < 4; ++i) {
    long rg = rbase + r0 + i;
    if (rg < nrows) {
#pragma unroll
      for (int j = 0; j < 4; ++j) hout[rg * 64 + c0 + j] = f2b(acc2[i][j]);
    }
  }
}

// ---------------------------------------------------------------------------
// Kernel 3: scatter into sorted order, XCD-sharded cursors; NT stores.
// pack: src (17 bits) | tgt<<17 (15 bits)
// ---------------------------------------------------------------------------
__global__ __launch_bounds__(256) void scat_k(const int* __restrict__ eidx,
                                              int* __restrict__ cursor8,
                                              const int* __restrict__ bsum,
                                              unsigned int* __restrict__ pkS,
                                              int* __restrict__ evp,
                                              long E, int G, int NB2) {
  __shared__ int bo[256];
  const int t = threadIdx.x;
  int v = (t < NB2) ? bsum[t] : 0;
  bo[t] = v;
  __syncthreads();
  for (int off = 1; off < 256; off <<= 1) {
    int x2 = (t >= off) ? bo[t - off] : 0;
    __syncthreads();
    bo[t] += x2;
    __syncthreads();
  }
  if (blockIdx.x == 0 && t == 0) *evp = bo[NB2 - 1];
  int excl = bo[t] - v;
  __syncthreads();
  bo[t] = excl;
  __syncthreads();
  const int c = blockIdx.x & 7;
  int* cur = cursor8 + (size_t)c * G;
  long i = (long)blockIdx.x * 256 + t;
  const long stride = (long)gridDim.x * 256;
  for (; i < E; i += stride) {
    int tg = eidx[E + i];
    if (tg >= 0 && tg < G) {
      int s = eidx[i];
      long j = ((long)tg << 3) | c;
      int p = atomicAdd(&cur[tg], 1) + bo[j >> 10];
      __builtin_nontemporal_store((unsigned int)s | ((unsigned int)tg << 17), pkS + p);
    }
  }
}

// ---------------------------------------------------------------------------
// Kernel 4: edge pipeline — R10 memory pattern, 2 barriers/tile.
// Per-wave LDS pool: ef1w[16][72] + hAw[16][136] (h_node cols 0..63,
// e_feat2 cols 64..127); msgfw f32[16][66] overlays hAw after S3. All stage
// rows are wave-private; only tgt_s boundary peeks cross waves, guarded by
// barrier A (post-gather) and barrier B (post-reduce). Geometry gather
// distributed: each wave's lanes 0..15 handle its own 16 edges.
// 31 KB LDS -> 5 blocks/CU.
// ---------------------------------------------------------------------------
#define ETILES 4

__global__ __launch_bounds__(256, 5) void edge_kernel(
    const void* node_pos, const void* grid_pos, const void* orient,
    const unsigned int* __restrict__ pkS, const int* __restrict__ evp,
    const u16* __restrict__ h_node, const u16* __restrict__ img,
    const float* __restrict__ fw, const int* __restrict__ flags,
    float* __restrict__ sums, int G)
{
  __shared__ __align__(16) u16 pool[4][3328];  // per wave 6656 B
  __shared__ float eaf[64][6];
  __shared__ float w1e[6][64];
  __shared__ float biasE[4][64];
  __shared__ int tgt_s[64];
  __shared__ int src_s[64];

  const int t = threadIdx.x;
  const int pf = flags[1], gf = flags[2], of = flags[3];
  const int Ev = *evp;
  for (int i = t; i < 384; i += 256) w1e[i / 64][i % 64] = fw[FW_EW1 + i];
  { int seg = t >> 6, cc = t & 63; biasE[seg][cc] = fw[FW_EB1 + seg * 64 + cc]; }
  __syncthreads();

  const int lane = t & 63, w = t >> 6;
  const int q = lane >> 4, c = lane & 15;
  const int m0 = w * 16;
  u16 (* __restrict__ ef1w)[72] = (u16 (*)[72])&pool[w][0];
  u16 (* __restrict__ hAw)[136] = (u16 (*)[136])&pool[w][1152];
  float (* __restrict__ msgfw)[66] = (float (*)[66])&pool[w][1152];  // 4224 <= 4352
  const u16* wE2 = img + IMG_EW2;
  const u16* wM1 = img + IMG_MW1;
  const u16* wM2 = img + IMG_MW2;
  const f32x4 z = {0.f, 0.f, 0.f, 0.f};

  for (int tile = 0; tile < ETILES; ++tile) {
    long base = ((long)blockIdx.x * ETILES + tile) * 64;
    if (base >= Ev) break;
    // gather: each wave's lanes 0..15 do the geometry for its own 16 edges
    if (lane < 16) {
      long eg = base + m0 + lane;
      int s = 0, tg = -1;
      if (eg < Ev) {
        unsigned int pk = pkS[eg];
        s = (int)(pk & 0x1FFFFu);
        tg = (int)(pk >> 17);
      }
      tgt_s[m0 + lane] = tg;
      src_s[m0 + lane] = s;
      int tgc = (tg >= 0) ? tg : 0;
      float ps[3], rel[3], tr[3];
#pragma unroll
      for (int i = 0; i < 3; ++i) {
        ps[i] = loadF(node_pos, (long)s * 3 + i, pf);
        rel[i] = loadF(grid_pos, (long)tgc * 3 + i, gf) - ps[i];
      }
#pragma unroll
      for (int j = 0; j < 3; ++j) tr[j] = 0.f;
#pragma unroll
      for (int i = 0; i < 3; ++i)
#pragma unroll
        for (int j = 0; j < 3; ++j)
          tr[j] = fmaf(rel[i], loadF(orient, (long)s * 9 + i * 3 + j, of), tr[j]);
      eaf[m0 + lane][0] = ps[0]; eaf[m0 + lane][1] = ps[1]; eaf[m0 + lane][2] = ps[2];
      eaf[m0 + lane][3] = tr[0]; eaf[m0 + lane][4] = tr[1]; eaf[m0 + lane][5] = tr[2];
    }
    __syncthreads();  // [A] tgt_s published for boundary peeks

    // staging: h_node rows into hAw cols 0..63 (wave-private rows, in-order)
    {
      int er = lane >> 2, ch = lane & 3;
      const u16* hp = h_node + (long)src_s[m0 + er] * 64 + ch * 16;
      short8 v0 = *(const short8*)hp;
      short8 v1 = *(const short8*)(hp + 8);
      *(short8*)&hAw[er][ch * 16] = v0;
      *(short8*)&hAw[er][ch * 16 + 8] = v1;
    }
    // S1: edge MLP layer1 (K=6) f32 VALU -> silu -> ef1w (bf16)
    {
      int e = lane >> 2, c0 = (lane & 3) * 16;
      int eb = m0 + e;
      float a0 = eaf[eb][0], a1 = eaf[eb][1], a2 = eaf[eb][2];
      float a3 = eaf[eb][3], a4 = eaf[eb][4], a5 = eaf[eb][5];
      __align__(16) u16 tmp[16];
#pragma unroll
      for (int j = 0; j < 16; ++j) {
        int cc = c0 + j;
        float acc = biasE[0][cc];
        acc = fmaf(a0, w1e[0][cc], acc);
        acc = fmaf(a1, w1e[1][cc], acc);
        acc = fmaf(a2, w1e[2][cc], acc);
        acc = fmaf(a3, w1e[3][cc], acc);
        acc = fmaf(a4, w1e[4][cc], acc);
        acc = fmaf(a5, w1e[5][cc], acc);
        tmp[j] = f2b(silu_f(acc));
      }
      *(short8*)&ef1w[e][c0] = *(const short8*)tmp;
      *(short8*)&ef1w[e][c0 + 8] = *(const short8*)(tmp + 8);
    }
    __builtin_amdgcn_wave_barrier();
    // S2: edge MLP layer2 (K=64) -> hAw cols 64..127
    {
      short8 a0 = *(const short8*)&ef1w[c][q * 8];
      short8 a1 = *(const short8*)&ef1w[c][32 + q * 8];
#pragma unroll
      for (int nt = 0; nt < 4; ++nt) {
        short8 b0 = *(const short8*)&wE2[(nt * 16 + c) * 72 + q * 8];
        short8 b1v = *(const short8*)&wE2[(nt * 16 + c) * 72 + 32 + q * 8];
        f32x4 acc = __builtin_amdgcn_mfma_f32_16x16x32_bf16(a0, b0, z, 0, 0, 0);
        acc = __builtin_amdgcn_mfma_f32_16x16x32_bf16(a1, b1v, acc, 0, 0, 0);
#pragma unroll
        for (int r = 0; r < 4; ++r) {
          int row = q * 4 + r, col = nt * 16 + c;
          hAw[row][64 + col] = f2b(acc[r] + biasE[1][col]);
        }
      }
    }
    __builtin_amdgcn_wave_barrier();
    // S3: msg MLP layer1 (K=128) -> silu -> ef1w
    {
      short8 a0 = *(const short8*)&hAw[c][q * 8];
      short8 a1 = *(const short8*)&hAw[c][32 + q * 8];
      short8 a2 = *(const short8*)&hAw[c][64 + q * 8];
      short8 a3 = *(const short8*)&hAw[c][96 + q * 8];
#pragma unroll
      for (int nt = 0; nt < 4; ++nt) {
        const u16* wp = &wM1[(nt * 16 + c) * 136];
        f32x4 acc = __builtin_amdgcn_mfma_f32_16x16x32_bf16(a0, *(const short8*)(wp + q * 8), z, 0, 0, 0);
        acc = __builtin_amdgcn_mfma_f32_16x16x32_bf16(a1, *(const short8*)(wp + 32 + q * 8), acc, 0, 0, 0);
        acc = __builtin_amdgcn_mfma_f32_16x16x32_bf16(a2, *(const short8*)(wp + 64 + q * 8), acc, 0, 0, 0);
        acc = __builtin_amdgcn_mfma_f32_16x16x32_bf16(a3, *(const short8*)(wp + 96 + q * 8), acc, 0, 0, 0);
#pragma unroll
        for (int r = 0; r < 4; ++r) {
          int row = q * 4 + r, col = nt * 16 + c;
          ef1w[row][col] = f2b(silu_f(acc[r] + biasE[2][col]));
        }
      }
    }
    __builtin_amdgcn_wave_barrier();   // hAw reads done; msgfw may overlay
    // S4: msg MLP layer2 (K=64) -> msgfw (f32, +bias) overlaying hAw
    {
      short8 a0 = *(const short8*)&ef1w[c][q * 8];
      short8 a1 = *(const short8*)&ef1w[c][32 + q * 8];
      __builtin_amdgcn_wave_barrier();   // pin reads before overlay writes
#pragma unroll
      for (int nt = 0; nt < 4; ++nt) {
        short8 b0 = *(const short8*)&wM2[(nt * 16 + c) * 72 + q * 8];
        short8 b1v = *(const short8*)&wM2[(nt * 16 + c) * 72 + 32 + q * 8];
        f32x4 acc = __builtin_amdgcn_mfma_f32_16x16x32_bf16(a0, b0, z, 0, 0, 0);
        acc = __builtin_amdgcn_mfma_f32_16x16x32_bf16(a1, b1v, acc, 0, 0, 0);
#pragma unroll
        for (int r = 0; r < 4; ++r) {
          int row = q * 4 + r, col = nt * 16 + c;
          msgfw[row][col] = acc[r] + biasE[3][col];
        }
      }
    }
    __builtin_amdgcn_wave_barrier();
    // Run-reduction over the wave's 16 rows; col = lane. Boundary targets
    // peeked from tgt_s (stable since barrier A).
    {
      int col = lane;
      int cur = tgt_s[m0];
      float run = msgfw[0][col];
      bool lopen = (m0 == 0) ? true : (tgt_s[m0 - 1] == cur);
#pragma unroll
      for (int r2 = 1; r2 < 16; ++r2) {
        int tg = tgt_s[m0 + r2];
        float v = msgfw[r2][col];
        if (tg == cur) {
          run += v;
        } else {
          if (cur >= 0) {
            if (lopen) unsafeAtomicAdd(&sums[(long)cur * 64 + col], run);
            else sums[(long)cur * 64 + col] = run;
          }
          cur = tg; run = v; lopen = false;
        }
      }
      bool ropen = (m0 + 16 >= 64) ? true : (tgt_s[m0 + 16] == cur);
      if (cur >= 0) {
        if (lopen || ropen) unsafeAtomicAdd(&sums[(long)cur * 64 + col], run);
        else sums[(long)cur * 64 + col] = run;
      }
    }
    __syncthreads();  // [B] reduces done before next tile's gather overwrites
  }
}

// ---------------------------------------------------------------------------
// Kernel 5: scatter-mean (sum of 8 count shards) + update MLP -> f32 out
// ---------------------------------------------------------------------------
__global__ __launch_bounds__(256) void upd_mlp(
    const float* __restrict__ sums, const int* __restrict__ cnt8,
    const float* __restrict__ fw, float* __restrict__ out, int nrows)
{
  __shared__ float xs[64][68];
  __shared__ float w1s[64][68];
  __shared__ float w2s[64][68];
  __shared__ float b1s[64];
  __shared__ float b2s[64];
  const int t = threadIdx.x;
  const long rbase = (long)blockIdx.x * 64;
  for (int i = t; i < 4096; i += 256) {
    int k = i >> 6, cc = i & 63;
    w1s[k][cc] = fw[FW_UW1 + i];
    w2s[k][cc] = fw[FW_UW2 + i];
  }
  if (t < 64) { b1s[t] = fw[FW_UB1 + t]; b2s[t] = fw[FW_UB2 + t]; }
  {
    int row = t >> 2, ch = t & 3;
    long rg = rbase + row;
    if (rg < nrows) {
      int cn = 0;
#pragma unroll
      for (int cc = 0; cc < 8; ++cc) cn += cnt8[(size_t)cc * nrows + rg];
      float inv = 1.0f / fmaxf((float)cn, 1.0f);
      const float* p = sums + rg * 64 + ch * 16;
#pragma unroll
      for (int m = 0; m < 16; ++m) xs[row][ch * 16 + m] = p[m] * inv;
    } else {
#pragma unroll
      for (int m = 0; m < 16; ++m) xs[row][ch * 16 + m] = 0.f;
    }
  }
  __syncthreads();
  const int r0 = (t >> 4) * 4, c0 = (t & 15) * 4;
  float acc[4][4];
#pragma unroll
  for (int i = 0; i < 4; ++i)
#pragma unroll
    for (int j = 0; j < 4; ++j) acc[i][j] = b1s[c0 + j];
  for (int k = 0; k < 64; ++k) {
    float w0 = w1s[k][c0], w1v = w1s[k][c0 + 1], w2v = w1s[k][c0 + 2], w3v = w1s[k][c0 + 3];
#pragma unroll
    for (int i = 0; i < 4; ++i) {
      float av = xs[r0 + i][k];
      acc[i][0] = fmaf(av, w0, acc[i][0]);
      acc[i][1] = fmaf(av, w1v, acc[i][1]);
      acc[i][2] = fmaf(av, w2v, acc[i][2]);
      acc[i][3] = fmaf(av, w3v, acc[i][3]);
    }
  }
  __syncthreads();
#pragma unroll
  for (int i = 0; i < 4; ++i)
#pragma unroll
    for (int j = 0; j < 4; ++j) xs[r0 + i][c0 + j] = silu_f(acc[i][j]);
  __syncthreads();
  float acc2[4][4];
#pragma unroll
  for (int i = 0; i < 4; ++i)
#pragma unroll
    for (int j = 0; j < 4; ++j) acc2[i][j] = b2s[c0 + j];
  for (int k = 0; k < 64; ++k) {
    float w0 = w2s[k][c0], w1v = w2s[k][c0 + 1], w2v = w2s[k][c0 + 2], w3v = w2s[k][c0 + 3];
#pragma unroll
    for (int i = 0; i < 4; ++i) {
      float av = xs[r0 + i][k];
      acc2[i][0] = fmaf(av, w0, acc2[i][0]);
      acc2[i][1] = fmaf(av, w1v, acc2[i][1]);
      acc2[i][2] = fmaf(av, w2v, acc2[i][2]);
      acc2[i][3] = fmaf(av, w3v, acc2[i][3]);
    }
  }
#pragma unroll
  for (int i = 0; i < 4; ++i) {
    long rg = rbase + r0 + i;
    if (rg < nrows) {
#pragma unroll
      for (int j = 0; j < 4; ++j) out[rg * 64 + c0 + j] = acc2[i][j];
    }
  }
}

// ---------------------------------------------------------------------------
extern "C" void kernel_launch(void* const* d_in, const int* in_sizes, int n_in,
                              void* d_out, int out_size, void* d_ws, size_t ws_size,
                              hipStream_t stream) {
  const int N = in_sizes[1] / 3;
  const int G = in_sizes[2] / 3;
  const long E = (long)in_sizes[4] / 2;
  const int NB2 = (int)((8L * G + 1023) / 1024);   // <=256 for G<=32768
  const int nodeBlocks = (N + 63) / 64;

  char* ws = (char*)d_ws;
  float* sums = (float*)ws;
  size_t off = (size_t)G * 256;
  int* cnt8 = (int*)(ws + off);     off += (size_t)G * 32;   // 8 shards
  int* cursor8 = (int*)(ws + off);  off += (size_t)G * 32;
  int* bsum = (int*)(ws + off);     off += 1024;
  int* evp = (int*)(ws + off);      off += 256;
  int* flags = (int*)(ws + off);    off += 256;
  unsigned int* pkS = (unsigned int*)(ws + off); off += (size_t)E * 4;
  u16* h_node = (u16*)(ws + off);   off += (size_t)N * 128;
  u16* img = (u16*)(ws + off);      off += (size_t)IMG_TOTAL * 2;
  float* fw = (float*)(ws + off);

  // zero sums + cnt8 (ws poisoned 0xAA before every timed launch)
  hipMemsetAsync(ws, 0, (size_t)G * 288, stream);

  Ptrs a;
  const int map[20] = {0,1,2,3, 5,6,7,8, 9,10,11,12, 13,14,15,16, 17,18,19,20};
  for (int i = 0; i < 20; ++i) { a.p[i] = d_in[map[i]]; a.n[i] = in_sizes[map[i]]; }

  hist_detect_k<<<HIST_BLOCKS + 20, 256, 0, stream>>>(
      a, (const int*)d_in[4], cnt8, flags, E, G);
  scan_prep_node_k<<<NB2 + PREP_BLOCKS + nodeBlocks, 256, 0, stream>>>(
      a, flags, cnt8, cursor8, bsum, img, fw, h_node, N, G, NB2);
  scat_k<<<1024, 256, 0, stream>>>((const int*)d_in[4], cursor8, bsum, pkS, evp, E, G, NB2);
  edge_kernel<<<(int)((E + ETILES * 64 - 1) / (ETILES * 64)), 256, 0, stream>>>(
      d_in[1], d_in[2], d_in[3], pkS, evp, h_node, img, fw, flags, sums, G);
  upd_mlp<<<(G + 63) / 64, 256, 0, stream>>>(sums, cnt8, fw, (float*)d_out, G);
}